// Round 1
// baseline (972.548 us; speedup 1.0000x reference)
//
#include <hip/hip_runtime.h>
#include <stdint.h>
#include <stddef.h>

// ---------------------------------------------------------------------------
// JanossyPoolingImproper: out[n,:2] = bo + (sum_p relu-MLP3(concat_j h[idx[n,P[p][j]]])) @ Wo
// Plan: gather -> X0 bf16 [3N,512] (row m = n*3+p) -> 3x bf16 MFMA GEMMs
// (128x128 tile, BK=64, global_load_lds w=16, XOR-swizzled LDS), layer-3
// epilogue fuses @Wo via LDS reduction + atomicAdd into out (init'd with bo).
// ---------------------------------------------------------------------------

typedef __attribute__((ext_vector_type(8))) short short8;
typedef __attribute__((ext_vector_type(4))) float f32x4;
typedef __attribute__((ext_vector_type(4))) float floatv4;
typedef __attribute__((ext_vector_type(8))) unsigned short ushort8;

#define GLOAD_LDS16(g, l)                                                      \
  __builtin_amdgcn_global_load_lds(                                            \
      (const __attribute__((address_space(1))) void*)(g),                      \
      (__attribute__((address_space(3))) void*)(l), 16, 0, 0)

__device__ __forceinline__ unsigned short f2bf(float f) {
  unsigned int u = __float_as_uint(f);
  u += 0x7fffu + ((u >> 16) & 1u);   // round-to-nearest-even
  return (unsigned short)(u >> 16);
}
__device__ __forceinline__ float bf2f(unsigned short s) {
  return __uint_as_float(((unsigned int)s) << 16);
}

#define NNODES   100000
#define MTOT     300000       // 3 perms * NNODES, row m = n*3 + p
#define HD       512

// --- weights: Wt[layer][n][k] = bf16(W[k][n]) --------------------------------
__global__ __launch_bounds__(256) void prep_weights(
    const float* __restrict__ W1, const float* __restrict__ W2,
    const float* __restrict__ W3, unsigned short* __restrict__ Wt) {
  int t = blockIdx.x * 256 + threadIdx.x;          // < 3*512*512
  int layer = t >> 18;
  int r = t & 262143;
  int n = r >> 9, k = r & 511;
  const float* W = layer == 0 ? W1 : (layer == 1 ? W2 : W3);
  Wt[t] = f2bf(W[k * 512 + n]);
}

// --- out init with bias ------------------------------------------------------
__global__ __launch_bounds__(256) void init_out(float* __restrict__ out,
                                                const float* __restrict__ bo) {
  int t = blockIdx.x * 256 + threadIdx.x;
  if (t < 2 * NNODES) out[t] = bo[t & 1];
}

// --- gather: X[mloc, j*128+c] = bf16(h[idx[n, P[p][j]], c]) ------------------
__global__ __launch_bounds__(256) void gather_x(
    const float* __restrict__ h, const int* __restrict__ idx,
    unsigned short* __restrict__ X, int m0) {
  const int PERM[3][4] = {{0, 1, 2, 3}, {2, 1, 3, 0}, {3, 1, 0, 2}};
  int t = threadIdx.x;
  int mloc = blockIdx.x * 4 + (t >> 6);
  int c = t & 63;
  int j = c >> 4;              // concat position 0..3
  int cc = (c & 15) * 8;       // col within 128, 8 bf16 per thread
  int mg = m0 + mloc;
  ushort8 o = {0, 0, 0, 0, 0, 0, 0, 0};
  if (mg < MTOT) {
    int n = mg / 3;
    int p = mg - n * 3;
    int src = idx[n * 4 + PERM[p][j]];
    const floatv4* hp = (const floatv4*)(h + (size_t)src * 128 + cc);
    floatv4 f0 = hp[0], f1 = hp[1];
#pragma unroll
    for (int e = 0; e < 4; ++e) {
      o[e] = f2bf(f0[e]);
      o[4 + e] = f2bf(f1[e]);
    }
  }
  *(ushort8*)(X + (size_t)mloc * HD + j * 128 + cc) = o;
}

// --- GEMM: C[128x128] tile of relu(A @ W + b); FINAL fuses @Wo + atomicAdd ---
// A: [RB*128, 512] bf16 row-major. Wt: [512,512] bf16, n-major (K contiguous).
// Block 256 thr = 4 waves in 2x2; wave = 64x64 = 4x4 frags of 16x16x32 MFMA.
// LDS tiles 128rows x 64k, 16B blocks XOR-swizzled by (row&7) -> staging stays
// lane-contiguous for global_load_lds AND ds_read_b128 is 2-way (free).
template <int FINAL>
__global__ __launch_bounds__(256) void gemm_mlp(
    const unsigned short* __restrict__ A, const unsigned short* __restrict__ Wt,
    const float* __restrict__ bias, unsigned short* __restrict__ Xout,
    float* __restrict__ out, const float* __restrict__ Wo, int m0glob) {
  __shared__ __align__(16) char smem[34816];
  char* sA = smem;           // 128*128B = 16384
  char* sB = smem + 16384;   // 16384

  const int t = threadIdx.x;
  int bx = blockIdx.x;
  // XCD swizzle: the 4 col-blocks of one row-block -> same XCD (bx%8),
  // adjacent dispatch slots -> A-stripe fetched once per XCD L2.
  int xcd = bx & 7, tq = bx >> 3;
  int cbk = tq & 3;
  int rb = xcd + ((tq >> 2) << 3);
  int n0 = cbk * 128;
  size_t arow0 = (size_t)rb * 128;

  int w = t >> 6, l = t & 63;
  int wm = (w >> 1) * 64, wn = (w & 1) * 64;
  int m16 = l & 15, q = l >> 4;

  f32x4 acc[4][4];
#pragma unroll
  for (int i = 0; i < 4; ++i)
#pragma unroll
    for (int j = 0; j < 4; ++j) acc[i][j] = (f32x4){0.f, 0.f, 0.f, 0.f};

  for (int kt = 0; kt < 8; ++kt) {
    int kb = kt * 64;
#pragma unroll
    for (int i = 0; i < 4; ++i) {   // stage A: 4 x (4 waves x 1KB) = 16KB
      int s = i * 256 + t;
      int r = s >> 3;
      int cl = (s & 7) ^ (r & 7);
      const unsigned short* ga = A + (arow0 + r) * HD + kb + cl * 8;
      GLOAD_LDS16(ga, sA + s * 16);
    }
#pragma unroll
    for (int i = 0; i < 4; ++i) {   // stage Wt tile
      int s = i * 256 + t;
      int r = s >> 3;
      int cl = (s & 7) ^ (r & 7);
      const unsigned short* ga = Wt + (size_t)(n0 + r) * HD + kb + cl * 8;
      GLOAD_LDS16(ga, sB + s * 16);
    }
    __syncthreads();
#pragma unroll
    for (int ks = 0; ks < 2; ++ks) {
      short8 af[4], bfr[4];
#pragma unroll
      for (int i = 0; i < 4; ++i) {
        int ra = wm + i * 16 + m16;
        int cbp = ((ks << 2) + q) ^ (m16 & 7);
        af[i] = *(const short8*)(sA + ra * 128 + cbp * 16);
        int rn = wn + i * 16 + m16;
        bfr[i] = *(const short8*)(sB + rn * 128 + cbp * 16);
      }
#pragma unroll
      for (int i = 0; i < 4; ++i)
#pragma unroll
        for (int j = 0; j < 4; ++j)
          acc[i][j] = __builtin_amdgcn_mfma_f32_16x16x32_bf16(
              af[i], bfr[j], acc[i][j], 0, 0, 0);
    }
    __syncthreads();
  }

  if (!FINAL) {
    // C/D frag: col = lane&15, row = q*4 + reg  (verified m89/m91 layout)
#pragma unroll
    for (int i = 0; i < 4; ++i)
#pragma unroll
      for (int j = 0; j < 4; ++j) {
        int coll = wn + j * 16 + m16;
        float bv = bias[n0 + coll];
#pragma unroll
        for (int r = 0; r < 4; ++r) {
          int rowl = wm + i * 16 + q * 4 + r;
          float v = fmaxf(acc[i][j][r] + bv, 0.f);
          Xout[(arow0 + rowl) * HD + n0 + coll] = f2bf(v);
        }
      }
  } else {
    // dump relu(x3) tile to LDS (bf16, stride 136 vs bank aliasing), then
    // 2 threads per row reduce 128 cols against Wo[:,jo] and atomicAdd.
    unsigned short* L = (unsigned short*)smem;
#pragma unroll
    for (int i = 0; i < 4; ++i)
#pragma unroll
      for (int j = 0; j < 4; ++j) {
        int coll = wn + j * 16 + m16;
        float bv = bias[n0 + coll];
#pragma unroll
        for (int r = 0; r < 4; ++r) {
          int rowl = wm + i * 16 + q * 4 + r;
          float v = fmaxf(acc[i][j][r] + bv, 0.f);
          L[rowl * 136 + coll] = f2bf(v);
        }
      }
    __syncthreads();
    int r2 = t >> 1, jo = t & 1;
    int grow = m0glob + rb * 128 + r2;
    if (grow < MTOT) {
      const unsigned short* Lr = L + r2 * 136;
      float s = 0.f;
#pragma unroll
      for (int c = 0; c < 128; c += 2) {
        unsigned int pair = *(const unsigned int*)(Lr + c);
        s += bf2f((unsigned short)(pair & 0xffffu)) * Wo[(n0 + c) * 2 + jo];
        s += bf2f((unsigned short)(pair >> 16)) * Wo[(n0 + c + 1) * 2 + jo];
      }
      int node = grow / 3;
      atomicAdd(out + node * 2 + jo, s);
    }
  }
}

extern "C" void kernel_launch(void* const* d_in, const int* in_sizes, int n_in,
                              void* d_out, int out_size, void* d_ws,
                              size_t ws_size, hipStream_t stream) {
  const float* h  = (const float*)d_in[0];
  const int*   ix = (const int*)d_in[1];
  const float* W1 = (const float*)d_in[2];
  const float* b1 = (const float*)d_in[3];
  const float* W2 = (const float*)d_in[4];
  const float* b2 = (const float*)d_in[5];
  const float* W3 = (const float*)d_in[6];
  const float* b3 = (const float*)d_in[7];
  const float* Wo = (const float*)d_in[8];
  const float* bo = (const float*)d_in[9];
  float* out = (float*)d_out;

  unsigned short* Wt = (unsigned short*)d_ws;        // 3*512*512 bf16
  const size_t wtBytes = (size_t)3 * 512 * 512 * 2;  // 1.5 MB
  unsigned short* bufs = (unsigned short*)((char*)d_ws + wtBytes);

  // chunk rows (multiple of 1024 so row-blocks per chunk % 8 == 0)
  size_t avail = ws_size > wtBytes ? ws_size - wtBytes : 0;
  size_t rowcap = avail / (2 * HD * sizeof(unsigned short));  // per buffer
  size_t Mc = (rowcap / 1024) * 1024;
  const size_t MPAD = 300032;  // 300000 rounded up to 1024
  if (Mc > MPAD) Mc = MPAD;
  if (Mc == 0) Mc = 1024;  // ws too small; best effort
  unsigned short* bufA = bufs;
  unsigned short* bufB = bufA + Mc * HD;

  prep_weights<<<3072, 256, 0, stream>>>(W1, W2, W3, Wt);
  init_out<<<(2 * NNODES + 255) / 256, 256, 0, stream>>>(out, bo);

  for (size_t m0 = 0; m0 < MTOT; m0 += Mc) {
    size_t rem = (size_t)MTOT - m0;
    size_t rows = rem < Mc ? ((rem + 1023) / 1024) * 1024 : Mc;
    int RB = (int)(rows / 128);
    gather_x<<<(int)(rows / 4), 256, 0, stream>>>(h, ix, bufA, (int)m0);
    gemm_mlp<0><<<RB * 4, 256, 0, stream>>>(bufA, Wt, b1, bufB, nullptr,
                                            nullptr, 0);
    gemm_mlp<0><<<RB * 4, 256, 0, stream>>>(bufB, Wt + 262144, b2, bufA,
                                            nullptr, nullptr, 0);
    gemm_mlp<1><<<RB * 4, 256, 0, stream>>>(bufA, Wt + 524288, b3, nullptr, out,
                                            Wo, (int)m0);
  }
}